// Round 1
// 801.648 us; speedup vs baseline: 1.1249x; 1.1249x over previous
//
#include <hip/hip_runtime.h>
#include <hip/hip_bf16.h>

// Problem constants
#define B_   256
#define L_   512
#define D_   768
#define H_   1000   // ATTN_H
#define NPAD 1024   // H_ padded to MFMA tile
#define XDIM 2324   // 2*D + D + 20
#define MAXPOS (B_*L_)   // 131072

typedef _Float16 half8 __attribute__((ext_vector_type(8)));
typedef float    f32x4 __attribute__((ext_vector_type(4)));

// ---------------------------------------------------------------------------
// Kernel 1: per-batch width scan (1 block). meta layout:
//   meta[0..255] offs | meta[256..511] start | meta[512..767] end | meta[768] npos
__global__ __launch_bounds__(256) void scan_kernel(const int* __restrict__ spans,
                                                   int* __restrict__ meta) {
    int b = threadIdx.x;
    int s = spans[2 * b], e = spans[2 * b + 1];
    s = min(max(s, 0), L_ - 1);
    e = min(max(e, s), L_ - 1);
    int w = e - s + 1;
    __shared__ int sw[256];
    sw[b] = w;
    __syncthreads();
    for (int d = 1; d < 256; d <<= 1) {
        int v = 0;
        if (b >= d) v = sw[b - d];
        __syncthreads();
        if (b >= d) sw[b] += v;
        __syncthreads();
    }
    meta[b]       = sw[b] - w;
    meta[256 + b] = s;
    meta[512 + b] = e;
    if (b == 255) meta[768] = sw[255];
}

// Kernel 2: compacted (b,l) position list
__global__ __launch_bounds__(256) void pos_fill(const int* __restrict__ meta,
                                                int* __restrict__ pos_list) {
    int b = blockIdx.x;
    int off = meta[b], start = meta[256 + b], end = meta[512 + b];
    int w = end - start + 1;
    for (int i = threadIdx.x; i < w; i += blockDim.x)
        pos_list[off + i] = (b << 16) | (start + i);
}

// ---------------------------------------------------------------------------
// Kernel 3: aw1 [768][1000] fp32 -> WbT [1024][768] f16 (transposed, zero-pad)
__global__ __launch_bounds__(256) void transpose_w(const float* __restrict__ aw1,
                                                   _Float16* __restrict__ WbT) {
    int k0 = blockIdx.x * 32, n0 = blockIdx.y * 32;
    int tx = threadIdx.x & 31, ty = threadIdx.x >> 5;   // 32 x 8
    __shared__ float T[32][33];
#pragma unroll
    for (int it = 0; it < 4; it++) {
        int k = k0 + ty + 8 * it;
        int n = n0 + tx;
        T[ty + 8 * it][tx] = (n < H_) ? aw1[(size_t)k * H_ + n] : 0.f;
    }
    __syncthreads();
#pragma unroll
    for (int it = 0; it < 4; it++) {
        int n = n0 + ty + 8 * it;
        WbT[(size_t)n * D_ + k0 + tx] = (_Float16)T[tx][ty + 8 * it];
    }
}

// ---------------------------------------------------------------------------
// Kernel 4 (v3): 128x128 MFMA GEMM, m97-style.
//   A: gathered embeds rows (fp32 -> f16, reg-staged -> LDS)
//   B: WbT staged via global_load_lds width 16 (linear LDS)
//   Double-buffered BK=32, 24 K-steps. Epilogue: bias+leaky+aw2-dot over the
//   block's 128 cols, shfl-reduce over l15, atomicAdd partial into attns[row].
#define BM   128
#define BN   128
#define BKT  32
#define NKST (D_ / BKT)   // 24

#define GLD_LDS16(gsrc, ldst) \
    __builtin_amdgcn_global_load_lds((const __attribute__((address_space(1))) void*)(gsrc), \
                                     (__attribute__((address_space(3))) void*)(ldst), 16, 0, 0)

__global__ __launch_bounds__(256) void attn_gemm_v3(
    const float* __restrict__ embeds, const _Float16* __restrict__ WbT,
    const float* __restrict__ ab1, const float* __restrict__ aw2,
    const int* __restrict__ pos_list, const int* __restrict__ meta,
    float* __restrict__ attns) {
    int npos = meta[768];
    int m0 = blockIdx.x * BM;
    if (m0 >= npos) return;
    int n0 = blockIdx.y * BN;
    int t = threadIdx.x;
    int lane = t & 63, w = t >> 6;
    int q = lane >> 4, l15 = lane & 15;
    int wr = w >> 1, wc = w & 1;          // wave sub-tile: rows wr*64, cols wc*64

    __shared__ alignas(16) _Float16 As[2][BM][BKT];   // [row][k], 64B rows
    __shared__ alignas(16) _Float16 Bs[2][BN * BKT];  // flat, row=col-of-C, 64B rows
    __shared__ unsigned rowoff[BM];

    if (t < BM) {
        unsigned off = 0;
        int m = m0 + t;
        if (m < npos) {
            int p = pos_list[m];
            off = (unsigned)((p >> 16) * (L_ * D_) + (p & 0xffff) * D_);
        }
        rowoff[t] = off;
    }
    __syncthreads();

    // A staging: thread t stages 16 floats of row (t>>1) at k-offset (t&1)*16
    const int arow = t >> 1;
    const int acol = (t & 1) * 16;
    const float* aptr = embeds + rowoff[arow] + acol;

    // B staging: thread t covers row n0+(t>>2), 8-f16 chunk (t&3); LDS dest is
    // wave-uniform base + lane*16 (linear layout matches Bs flat indexing).
    const _Float16* bptr = WbT + (size_t)(n0 + (t >> 2)) * D_ + (t & 3) * 8;

    float4 ar0, ar1, ar2, ar3;
    auto loadA = [&](int k0) {
        const float* p = aptr + k0;
        ar0 = *(const float4*)(p + 0);
        ar1 = *(const float4*)(p + 4);
        ar2 = *(const float4*)(p + 8);
        ar3 = *(const float4*)(p + 12);
    };
    auto writeA = [&](int bbuf) {
        half8 h0, h1;
        h0[0] = (_Float16)ar0.x; h0[1] = (_Float16)ar0.y;
        h0[2] = (_Float16)ar0.z; h0[3] = (_Float16)ar0.w;
        h0[4] = (_Float16)ar1.x; h0[5] = (_Float16)ar1.y;
        h0[6] = (_Float16)ar1.z; h0[7] = (_Float16)ar1.w;
        h1[0] = (_Float16)ar2.x; h1[1] = (_Float16)ar2.y;
        h1[2] = (_Float16)ar2.z; h1[3] = (_Float16)ar2.w;
        h1[4] = (_Float16)ar3.x; h1[5] = (_Float16)ar3.y;
        h1[6] = (_Float16)ar3.z; h1[7] = (_Float16)ar3.w;
        *(half8*)&As[bbuf][arow][acol]     = h0;
        *(half8*)&As[bbuf][arow][acol + 8] = h1;
    };
    auto issueB = [&](int bbuf, int k0) {
        const _Float16* s0 = bptr + k0;
        _Float16* d0 = &Bs[bbuf][0] + w * 512;   // w*1024 bytes, wave-uniform
        GLD_LDS16(s0, d0);
        const _Float16* s1 = s0 + (size_t)64 * D_;
        _Float16* d1 = d0 + 2048;                // +4096 bytes (rows 64..127)
        GLD_LDS16(s1, d1);
    };

    f32x4 acc[4][4];
#pragma unroll
    for (int mi = 0; mi < 4; mi++)
#pragma unroll
        for (int ni = 0; ni < 4; ni++) acc[mi][ni] = (f32x4){0.f, 0.f, 0.f, 0.f};

    auto compute = [&](int bbuf) {
        half8 af[4], bf[4];
#pragma unroll
        for (int mi = 0; mi < 4; mi++)
            af[mi] = *(const half8*)&As[bbuf][wr * 64 + mi * 16 + l15][q * 8];
#pragma unroll
        for (int ni = 0; ni < 4; ni++)
            bf[ni] = *(const half8*)&Bs[bbuf][((wc * 64 + ni * 16 + l15) << 5) + q * 8];
#pragma unroll
        for (int mi = 0; mi < 4; mi++)
#pragma unroll
            for (int ni = 0; ni < 4; ni++)
                acc[mi][ni] = __builtin_amdgcn_mfma_f32_16x16x32_f16(
                    af[mi], bf[ni], acc[mi][ni], 0, 0, 0);
    };

    // prologue: stage tile 0
    issueB(0, 0);
    loadA(0);
    writeA(0);
    __syncthreads();

    int buf = 0;
#pragma unroll 2
    for (int ks = 0; ks < NKST - 1; ks++) {
        int kn = (ks + 1) * BKT;
        issueB(buf ^ 1, kn);   // async B prefetch into other buffer
        loadA(kn);             // A prefetch into registers
        compute(buf);
        writeA(buf ^ 1);       // cvt + LDS write after MFMAs
        __syncthreads();       // drains vmcnt (global_load_lds) + lgkmcnt
        buf ^= 1;
    }
    compute(buf);              // last tile, no prefetch

    // epilogue: attns[row] += sum_cols leaky(acc + ab1[col]) * aw2[col]
    int colb = n0 + wc * 64;
    float bj[4], aj[4];
#pragma unroll
    for (int ni = 0; ni < 4; ni++) {
        int col = colb + ni * 16 + l15;
        bool v = col < H_;
        bj[ni] = v ? ab1[col] : 0.f;
        aj[ni] = v ? aw2[col] : 0.f;
    }
#pragma unroll
    for (int mi = 0; mi < 4; mi++) {
#pragma unroll
        for (int r = 0; r < 4; r++) {
            float p = 0.f;
#pragma unroll
            for (int ni = 0; ni < 4; ni++) {
                float h = acc[mi][ni][r] + bj[ni];
                h = h > 0.f ? h : 0.01f * h;
                p += h * aj[ni];
            }
            p += __shfl_xor(p, 1);
            p += __shfl_xor(p, 2);
            p += __shfl_xor(p, 4);
            p += __shfl_xor(p, 8);
            if (l15 == 0) {
                int row = m0 + wr * 64 + mi * 16 + q * 4 + r;
                if (row < npos) atomicAdd(&attns[row], p);
            }
        }
    }
}

// ---------------------------------------------------------------------------
// Kernel 5: softmax + weighted sum, 3 dim-slices per batch. (R4-validated)
__global__ __launch_bounds__(256) void build_x(
    const float* __restrict__ embeds, const float* __restrict__ attns,
    const int* __restrict__ meta, const float* __restrict__ width_emb,
    float* __restrict__ x) {
    int b = blockIdx.x, s = blockIdx.y, t = threadIdx.x;
    int off = meta[b], start = meta[256 + b], end = meta[512 + b];
    int w = end - start + 1;
    __shared__ float sv[512];
    __shared__ float red[256];
    for (int i = t; i < w; i += 256) sv[i] = attns[off + i];
    __syncthreads();
    float m = -3.0e38f;
    for (int i = t; i < w; i += 256) m = fmaxf(m, sv[i]);
    red[t] = m;
    __syncthreads();
    for (int st = 128; st > 0; st >>= 1) {
        if (t < st) red[t] = fmaxf(red[t], red[t + st]);
        __syncthreads();
    }
    float mx = red[0];
    __syncthreads();
    float ssum = 0.f;
    for (int i = t; i < w; i += 256) {
        float e = __expf(sv[i] - mx);
        sv[i] = e;
        ssum += e;
    }
    red[t] = ssum;
    __syncthreads();
    for (int st = 128; st > 0; st >>= 1) {
        if (t < st) red[t] += red[t + st];
        __syncthreads();
    }
    float inv = 1.0f / red[0];
    __syncthreads();

    int dim = s * 256 + t;
    const float* base = embeds + ((size_t)b * L_ + start) * D_ + dim;
    float acc = 0.f;
    int i = 0;
    for (; i + 3 < w; i += 4) {
        float w0 = sv[i], w1 = sv[i + 1], w2 = sv[i + 2], w3 = sv[i + 3];
        const float* p = base + (size_t)i * D_;
        acc += w0 * p[0] + w1 * p[D_] + w2 * p[2 * D_] + w3 * p[3 * D_];
    }
    for (; i < w; i++) acc += sv[i] * base[(size_t)i * D_];

    float* xb = x + (size_t)b * XDIM;
    xb[1536 + dim] = acc * inv;
    xb[dim]        = base[0];
    xb[768 + dim]  = embeds[((size_t)b * L_ + end) * D_ + dim];
    if (s == 0 && t < 20) {
        const int bins[15] = {1, 2, 3, 4, 5, 6, 7, 8, 12, 16, 20, 24, 32, 64, 128};
        int idx = 0;
#pragma unroll
        for (int q2 = 0; q2 < 15; q2++) idx += (w > bins[q2]);
        xb[2304 + t] = width_emb[idx * 20 + t];
    }
}

// ---------------------------------------------------------------------------
// Kernel 6: split-K fp32 GEMM. Block = 64x64 output tile x K-chunk.
// Partials atomicAdd'ed into zeroed out buffer. KT=16, double-buffered staging.
__global__ __launch_bounds__(256) void mlp_gemm_sk(
    const float* __restrict__ A, const float* __restrict__ W,
    float* __restrict__ out, int M, int N, int K, int kchunk) {
    __shared__ float As[16][68];   // As[k][m], padded
    __shared__ float Ws[16][64];   // Ws[k][n]
    int t = threadIdx.x;
    int tx = t & 15, ty = t >> 4;
    int m0 = blockIdx.x * 64, n0 = blockIdx.y * 64;
    int ks = blockIdx.z * kchunk;
    int ke = min(ks + kchunk, K);
    if (ks >= ke) return;
    int ar = t >> 2, akc = (t & 3) * 4;     // A: row ar, 4 k's
    int wk = t >> 4, wnc = (t & 15) * 4;    // W: k wk, 4 n's
    bool n4 = ((N & 3) == 0);

    float acc[4][4];
#pragma unroll
    for (int i = 0; i < 4; i++)
#pragma unroll
        for (int j = 0; j < 4; j++) acc[i][j] = 0.f;

    auto loadA = [&](int k0) -> float4 {
        float4 r = make_float4(0.f, 0.f, 0.f, 0.f);
        int k = k0 + akc;                    // akc, ke multiples of 4
        if (k < ke) r = *(const float4*)(A + (size_t)(m0 + ar) * K + k);
        return r;
    };
    auto loadW = [&](int k0) -> float4 {
        float4 r = make_float4(0.f, 0.f, 0.f, 0.f);
        int k = k0 + wk;
        if (k < ke) {
            int n = n0 + wnc;
            const float* p = W + (size_t)k * N + n;
            if (n4) {
                r = *(const float4*)p;       // full tiles when N%4==0 (N>=64 cases)
            } else {
                float tmp[4];
#pragma unroll
                for (int q2 = 0; q2 < 4; q2++)
                    tmp[q2] = (n + q2 < N) ? p[q2] : 0.f;
                r = make_float4(tmp[0], tmp[1], tmp[2], tmp[3]);
            }
        }
        return r;
    };

    float4 aR = loadA(ks), wR = loadW(ks);
    for (int k0 = ks; k0 < ke; k0 += 16) {
        As[akc + 0][ar] = aR.x;
        As[akc + 1][ar] = aR.y;
        As[akc + 2][ar] = aR.z;
        As[akc + 3][ar] = aR.w;
        *(float4*)&Ws[wk][wnc] = wR;
        __syncthreads();
        if (k0 + 16 < ke) { aR = loadA(k0 + 16); wR = loadW(k0 + 16); }
#pragma unroll
        for (int kk = 0; kk < 16; kk++) {
            float4 a = *(const float4*)&As[kk][ty * 4];
            float4 b = *(const float4*)&Ws[kk][tx * 4];
            float av[4] = {a.x, a.y, a.z, a.w};
            float bv[4] = {b.x, b.y, b.z, b.w};
#pragma unroll
            for (int i = 0; i < 4; i++)
#pragma unroll
                for (int j = 0; j < 4; j++) acc[i][j] += av[i] * bv[j];
        }
        __syncthreads();
    }
#pragma unroll
    for (int i = 0; i < 4; i++) {
#pragma unroll
        for (int j = 0; j < 4; j++) {
            int nn = n0 + tx * 4 + j;
            if (nn < N)
                atomicAdd(&out[(size_t)(m0 + ty * 4 + i) * N + nn], acc[i][j]);
        }
    }
}

// Kernel 7: elementwise bias (+ optional leaky), src -> dst
__global__ __launch_bounds__(256) void bias_act(
    const float* __restrict__ src, const float* __restrict__ bias,
    float* __restrict__ dst, int total, int N, int leaky) {
    int i = blockIdx.x * 256 + threadIdx.x;
    int stride = gridDim.x * 256;
    for (; i < total; i += stride) {
        float v = src[i] + bias[i % N];
        if (leaky) v = v > 0.f ? v : 0.01f * v;
        dst[i] = v;
    }
}

// ---------------------------------------------------------------------------
extern "C" void kernel_launch(void* const* d_in, const int* in_sizes, int n_in,
                              void* d_out, int out_size, void* d_ws, size_t ws_size,
                              hipStream_t stream) {
    const float* embeds    = (const float*)d_in[0];
    const int*   spans     = (const int*)d_in[1];   // int64 ref -> int32 device
    const float* aw1       = (const float*)d_in[2];
    const float* ab1       = (const float*)d_in[3];
    const float* aw2       = (const float*)d_in[4];
    // d_in[5] = ab2: softmax shift-invariant -> unused
    const float* width_emb = (const float*)d_in[6];
    const float* sw1 = (const float*)d_in[7],  *sb1 = (const float*)d_in[8];
    const float* sw2 = (const float*)d_in[9],  *sb2 = (const float*)d_in[10];
    const float* sw3 = (const float*)d_in[11], *sb3 = (const float*)d_in[12];
    const float* sw4 = (const float*)d_in[13], *sb4 = (const float*)d_in[14];
    float* out = (float*)d_out;

    char* ws = (char*)d_ws;
    float*     attns    = (float*)ws;                              // 512 KB
    int*       pos_list = (int*)(ws + (size_t)MAXPOS * 4);         // 512 KB
    int*       meta     = (int*)(ws + (size_t)MAXPOS * 8);         // 4 KB
    _Float16*  WbT      = (_Float16*)(ws + (size_t)MAXPOS * 8 + 4096);  // 1.5 MB
    float* x  = (float*)(ws + (size_t)MAXPOS * 8 + 4096 + (size_t)NPAD * D_ * 2);
    float* y1 = x + (size_t)B_ * XDIM;        // 256*1024
    float* y2 = y1 + (size_t)B_ * 1024;       // 256*512
    float* y3 = y2 + (size_t)B_ * 512;        // 256*256
    float* y4 = y3 + (size_t)B_ * 256;        // 256*30
    size_t ybytes = ((size_t)B_ * (1024 + 512 + 256 + 30)) * 4;

    hipMemsetAsync(y1, 0, ybytes, stream);    // split-K accumulators
    hipMemsetAsync(attns, 0, (size_t)MAXPOS * 4, stream);  // attn partial sums
    scan_kernel<<<1, 256, 0, stream>>>(spans, meta);
    pos_fill<<<B_, 256, 0, stream>>>(meta, pos_list);
    transpose_w<<<dim3(D_ / 32, NPAD / 32), 256, 0, stream>>>(aw1, WbT);
    attn_gemm_v3<<<dim3(MAXPOS / BM, NPAD / BN), 256, 0, stream>>>(
        embeds, WbT, ab1, aw2, pos_list, meta, attns);
    build_x<<<dim3(B_, 3), 256, 0, stream>>>(embeds, attns, meta, width_emb, x);

    mlp_gemm_sk<<<dim3(4, 16, 8), 256, 0, stream>>>(x,  sw1, y1, B_, 1024, XDIM, 292);
    bias_act<<<256, 256, 0, stream>>>(y1, sb1, y1, B_ * 1024, 1024, 1);
    mlp_gemm_sk<<<dim3(4, 8, 8), 256, 0, stream>>>(y1, sw2, y2, B_, 512, 1024, 128);
    bias_act<<<128, 256, 0, stream>>>(y2, sb2, y2, B_ * 512, 512, 1);
    mlp_gemm_sk<<<dim3(4, 4, 8), 256, 0, stream>>>(y2, sw3, y3, B_, 256, 512, 64);
    bias_act<<<64, 256, 0, stream>>>(y3, sb3, y3, B_ * 256, 256, 1);
    mlp_gemm_sk<<<dim3(4, 1, 8), 256, 0, stream>>>(y3, sw4, y4, B_, 30, 256, 32);
    bias_act<<<30, 256, 0, stream>>>(y4, sb4, out, B_ * 30, 30, 0);
}

// Round 2
// 731.091 us; speedup vs baseline: 1.2334x; 1.0965x over previous
//
#include <hip/hip_runtime.h>
#include <hip/hip_bf16.h>

// Problem constants
#define B_   256
#define L_   512
#define D_   768
#define H_   1000   // ATTN_H
#define NPAD 1024   // H_ padded to MFMA tile
#define XDIM 2324   // 2*D + D + 20
#define MAXPOS (B_*L_)   // 131072

typedef _Float16 half8 __attribute__((ext_vector_type(8)));
typedef float    f32x4 __attribute__((ext_vector_type(4)));

// ---------------------------------------------------------------------------
// Kernel 1: per-batch width scan (1 block). meta layout:
//   meta[0..255] offs | meta[256..511] start | meta[512..767] end | meta[768] npos
__global__ __launch_bounds__(256) void scan_kernel(const int* __restrict__ spans,
                                                   int* __restrict__ meta) {
    int b = threadIdx.x;
    int s = spans[2 * b], e = spans[2 * b + 1];
    s = min(max(s, 0), L_ - 1);
    e = min(max(e, s), L_ - 1);
    int w = e - s + 1;
    __shared__ int sw[256];
    sw[b] = w;
    __syncthreads();
    for (int d = 1; d < 256; d <<= 1) {
        int v = 0;
        if (b >= d) v = sw[b - d];
        __syncthreads();
        if (b >= d) sw[b] += v;
        __syncthreads();
    }
    meta[b]       = sw[b] - w;
    meta[256 + b] = s;
    meta[512 + b] = e;
    if (b == 255) meta[768] = sw[255];
}

// Kernel 2: compacted (b,l) position list
__global__ __launch_bounds__(256) void pos_fill(const int* __restrict__ meta,
                                                int* __restrict__ pos_list) {
    int b = blockIdx.x;
    int off = meta[b], start = meta[256 + b], end = meta[512 + b];
    int w = end - start + 1;
    for (int i = threadIdx.x; i < w; i += blockDim.x)
        pos_list[off + i] = (b << 16) | (start + i);
}

// ---------------------------------------------------------------------------
// Kernel 3: aw1 [768][1000] fp32 -> WbT [1024][768] f16 (transposed, zero-pad)
__global__ __launch_bounds__(256) void transpose_w(const float* __restrict__ aw1,
                                                   _Float16* __restrict__ WbT) {
    int k0 = blockIdx.x * 32, n0 = blockIdx.y * 32;
    int tx = threadIdx.x & 31, ty = threadIdx.x >> 5;   // 32 x 8
    __shared__ float T[32][33];
#pragma unroll
    for (int it = 0; it < 4; it++) {
        int k = k0 + ty + 8 * it;
        int n = n0 + tx;
        T[ty + 8 * it][tx] = (n < H_) ? aw1[(size_t)k * H_ + n] : 0.f;
    }
    __syncthreads();
#pragma unroll
    for (int it = 0; it < 4; it++) {
        int n = n0 + ty + 8 * it;
        WbT[(size_t)n * D_ + k0 + tx] = (_Float16)T[tx][ty + 8 * it];
    }
}

// ---------------------------------------------------------------------------
// Kernel 4 (v4): 128x256 MFMA GEMM, 512 threads = 8 waves (2 row x 4 col).
//   A: gathered embeds rows (fp32 -> f16, reg-staged -> LDS), gathered only
//      NPAD/BN = 4 times total (was 8 with BN=128).
//   B: WbT staged via global_load_lds width 16 (linear LDS)
//   Double-buffered BK=32, 24 K-steps. Epilogue: bias+leaky+aw2-dot,
//   shfl-reduce over l15, atomicAdd partial into attns[row].
#define BM   128
#define BN   256
#define BKT  32
#define NKST (D_ / BKT)   // 24

#define GLD_LDS16(gsrc, ldst) \
    __builtin_amdgcn_global_load_lds((const __attribute__((address_space(1))) void*)(gsrc), \
                                     (__attribute__((address_space(3))) void*)(ldst), 16, 0, 0)

__global__ __launch_bounds__(512, 4) void attn_gemm_v4(
    const float* __restrict__ embeds, const _Float16* __restrict__ WbT,
    const float* __restrict__ ab1, const float* __restrict__ aw2,
    const int* __restrict__ pos_list, const int* __restrict__ meta,
    float* __restrict__ attns) {
    int npos = meta[768];
    int m0 = blockIdx.x * BM;
    if (m0 >= npos) return;
    int n0 = blockIdx.y * BN;
    int t = threadIdx.x;
    int lane = t & 63, w = t >> 6;        // wave id 0..7
    int q = lane >> 4, l15 = lane & 15;
    int wr = w >> 2, wc = w & 3;          // wave sub-tile: rows wr*64, cols wc*64

    __shared__ alignas(16) _Float16 As[2][BM][BKT];   // 16 KB
    __shared__ alignas(16) _Float16 Bs[2][BN * BKT];  // 32 KB, row=col-of-C, 64B rows
    __shared__ unsigned rowoff[BM];

    if (t < BM) {
        unsigned off = 0;
        int m = m0 + t;
        if (m < npos) {
            int p = pos_list[m];
            off = (unsigned)((p >> 16) * (L_ * D_) + (p & 0xffff) * D_);
        }
        rowoff[t] = off;
    }
    __syncthreads();

    // A staging: thread t stages 8 floats of row (t>>2) at k-offset (t&3)*8
    const int arow = t >> 2;
    const int acol = (t & 3) * 8;
    const float* aptr = embeds + rowoff[arow] + acol;

    // B staging: 256 rows x 64B per buffer = 1024 x 16B chunks; thread t covers
    // chunk t (rows 0..127) and chunk t+512 (rows 128..255). LDS dest is
    // wave-uniform base + lane*16 (linear layout matches Bs flat indexing).
    const _Float16* bptr = WbT + (size_t)(n0 + (t >> 2)) * D_ + (t & 3) * 8;

    float4 ar0, ar1;
    auto loadA = [&](int k0) {
        const float* p = aptr + k0;
        ar0 = *(const float4*)(p + 0);
        ar1 = *(const float4*)(p + 4);
    };
    auto writeA = [&](int bbuf) {
        half8 h0;
        h0[0] = (_Float16)ar0.x; h0[1] = (_Float16)ar0.y;
        h0[2] = (_Float16)ar0.z; h0[3] = (_Float16)ar0.w;
        h0[4] = (_Float16)ar1.x; h0[5] = (_Float16)ar1.y;
        h0[6] = (_Float16)ar1.z; h0[7] = (_Float16)ar1.w;
        *(half8*)&As[bbuf][arow][acol] = h0;
    };
    auto issueB = [&](int bbuf, int k0) {
        const _Float16* s0 = bptr + k0;
        _Float16* d0 = &Bs[bbuf][0] + w * 512;   // w*1024 bytes, wave-uniform
        GLD_LDS16(s0, d0);
        const _Float16* s1 = s0 + (size_t)128 * D_;
        _Float16* d1 = d0 + 4096;                // +8192 bytes (rows 128..255)
        GLD_LDS16(s1, d1);
    };

    f32x4 acc[4][4];
#pragma unroll
    for (int mi = 0; mi < 4; mi++)
#pragma unroll
        for (int ni = 0; ni < 4; ni++) acc[mi][ni] = (f32x4){0.f, 0.f, 0.f, 0.f};

    auto compute = [&](int bbuf) {
        half8 af[4], bf[4];
#pragma unroll
        for (int mi = 0; mi < 4; mi++)
            af[mi] = *(const half8*)&As[bbuf][wr * 64 + mi * 16 + l15][q * 8];
#pragma unroll
        for (int ni = 0; ni < 4; ni++)
            bf[ni] = *(const half8*)&Bs[bbuf][((wc * 64 + ni * 16 + l15) << 5) + q * 8];
#pragma unroll
        for (int mi = 0; mi < 4; mi++)
#pragma unroll
            for (int ni = 0; ni < 4; ni++)
                acc[mi][ni] = __builtin_amdgcn_mfma_f32_16x16x32_f16(
                    af[mi], bf[ni], acc[mi][ni], 0, 0, 0);
    };

    // prologue: stage tile 0
    issueB(0, 0);
    loadA(0);
    writeA(0);
    __syncthreads();

    int buf = 0;
#pragma unroll 2
    for (int ks = 0; ks < NKST - 1; ks++) {
        int kn = (ks + 1) * BKT;
        issueB(buf ^ 1, kn);   // async B prefetch into other buffer
        loadA(kn);             // A prefetch into registers
        compute(buf);
        writeA(buf ^ 1);       // cvt + LDS write after MFMAs
        __syncthreads();       // drains vmcnt (global_load_lds) + lgkmcnt
        buf ^= 1;
    }
    compute(buf);              // last tile, no prefetch

    // epilogue: attns[row] += sum_cols leaky(acc + ab1[col]) * aw2[col]
    int colb = n0 + wc * 64;
    float bj[4], aj[4];
#pragma unroll
    for (int ni = 0; ni < 4; ni++) {
        int col = colb + ni * 16 + l15;
        bool v = col < H_;
        bj[ni] = v ? ab1[col] : 0.f;
        aj[ni] = v ? aw2[col] : 0.f;
    }
#pragma unroll
    for (int mi = 0; mi < 4; mi++) {
#pragma unroll
        for (int r = 0; r < 4; r++) {
            float p = 0.f;
#pragma unroll
            for (int ni = 0; ni < 4; ni++) {
                float h = acc[mi][ni][r] + bj[ni];
                h = h > 0.f ? h : 0.01f * h;
                p += h * aj[ni];
            }
            p += __shfl_xor(p, 1);
            p += __shfl_xor(p, 2);
            p += __shfl_xor(p, 4);
            p += __shfl_xor(p, 8);
            if (l15 == 0) {
                int row = m0 + wr * 64 + mi * 16 + q * 4 + r;
                if (row < npos) atomicAdd(&attns[row], p);
            }
        }
    }
}

// ---------------------------------------------------------------------------
// Kernel 5: softmax + weighted sum, 3 dim-slices per batch. (R4-validated)
__global__ __launch_bounds__(256) void build_x(
    const float* __restrict__ embeds, const float* __restrict__ attns,
    const int* __restrict__ meta, const float* __restrict__ width_emb,
    float* __restrict__ x) {
    int b = blockIdx.x, s = blockIdx.y, t = threadIdx.x;
    int off = meta[b], start = meta[256 + b], end = meta[512 + b];
    int w = end - start + 1;
    __shared__ float sv[512];
    __shared__ float red[256];
    for (int i = t; i < w; i += 256) sv[i] = attns[off + i];
    __syncthreads();
    float m = -3.0e38f;
    for (int i = t; i < w; i += 256) m = fmaxf(m, sv[i]);
    red[t] = m;
    __syncthreads();
    for (int st = 128; st > 0; st >>= 1) {
        if (t < st) red[t] = fmaxf(red[t], red[t + st]);
        __syncthreads();
    }
    float mx = red[0];
    __syncthreads();
    float ssum = 0.f;
    for (int i = t; i < w; i += 256) {
        float e = __expf(sv[i] - mx);
        sv[i] = e;
        ssum += e;
    }
    red[t] = ssum;
    __syncthreads();
    for (int st = 128; st > 0; st >>= 1) {
        if (t < st) red[t] += red[t + st];
        __syncthreads();
    }
    float inv = 1.0f / red[0];
    __syncthreads();

    int dim = s * 256 + t;
    const float* base = embeds + ((size_t)b * L_ + start) * D_ + dim;
    float acc = 0.f;
    int i = 0;
    for (; i + 3 < w; i += 4) {
        float w0 = sv[i], w1 = sv[i + 1], w2 = sv[i + 2], w3 = sv[i + 3];
        const float* p = base + (size_t)i * D_;
        acc += w0 * p[0] + w1 * p[D_] + w2 * p[2 * D_] + w3 * p[3 * D_];
    }
    for (; i < w; i++) acc += sv[i] * base[(size_t)i * D_];

    float* xb = x + (size_t)b * XDIM;
    xb[1536 + dim] = acc * inv;
    xb[dim]        = base[0];
    xb[768 + dim]  = embeds[((size_t)b * L_ + end) * D_ + dim];
    if (s == 0 && t < 20) {
        const int bins[15] = {1, 2, 3, 4, 5, 6, 7, 8, 12, 16, 20, 24, 32, 64, 128};
        int idx = 0;
#pragma unroll
        for (int q2 = 0; q2 < 15; q2++) idx += (w > bins[q2]);
        xb[2304 + t] = width_emb[idx * 20 + t];
    }
}

// ---------------------------------------------------------------------------
// Kernel 6: split-K fp32 GEMM. Block = 64x64 output tile x K-chunk.
// Partials atomicAdd'ed into zeroed out buffer. KT=16, double-buffered staging.
// abias/aleaky: fused bias+leaky applied to A rows on load (prev layer's
// epilogue), so the separate bias_act pass between layers is eliminated.
__global__ __launch_bounds__(256) void mlp_gemm_sk(
    const float* __restrict__ A, const float* __restrict__ abias, int aleaky,
    const float* __restrict__ W, float* __restrict__ out,
    int M, int N, int K, int kchunk) {
    __shared__ float As[16][68];   // As[k][m], padded
    __shared__ float Ws[16][64];   // Ws[k][n]
    int t = threadIdx.x;
    int tx = t & 15, ty = t >> 4;
    int m0 = blockIdx.x * 64, n0 = blockIdx.y * 64;
    int ks = blockIdx.z * kchunk;
    int ke = min(ks + kchunk, K);
    if (ks >= ke) return;
    int ar = t >> 2, akc = (t & 3) * 4;     // A: row ar, 4 k's
    int wk = t >> 4, wnc = (t & 15) * 4;    // W: k wk, 4 n's
    bool n4 = ((N & 3) == 0);

    float acc[4][4];
#pragma unroll
    for (int i = 0; i < 4; i++)
#pragma unroll
        for (int j = 0; j < 4; j++) acc[i][j] = 0.f;

    auto loadA = [&](int k0) -> float4 {
        float4 r = make_float4(0.f, 0.f, 0.f, 0.f);
        int k = k0 + akc;                    // akc, ke multiples of 4
        if (k < ke) {
            r = *(const float4*)(A + (size_t)(m0 + ar) * K + k);
            if (abias) {
                r.x += abias[k];     r.y += abias[k + 1];
                r.z += abias[k + 2]; r.w += abias[k + 3];
                if (aleaky) {
                    r.x = r.x > 0.f ? r.x : 0.01f * r.x;
                    r.y = r.y > 0.f ? r.y : 0.01f * r.y;
                    r.z = r.z > 0.f ? r.z : 0.01f * r.z;
                    r.w = r.w > 0.f ? r.w : 0.01f * r.w;
                }
            }
        }
        return r;
    };
    auto loadW = [&](int k0) -> float4 {
        float4 r = make_float4(0.f, 0.f, 0.f, 0.f);
        int k = k0 + wk;
        if (k < ke) {
            int n = n0 + wnc;
            const float* p = W + (size_t)k * N + n;
            if (n4) {
                r = *(const float4*)p;       // full tiles when N%4==0 (N>=64 cases)
            } else {
                float tmp[4];
#pragma unroll
                for (int q2 = 0; q2 < 4; q2++)
                    tmp[q2] = (n + q2 < N) ? p[q2] : 0.f;
                r = make_float4(tmp[0], tmp[1], tmp[2], tmp[3]);
            }
        }
        return r;
    };

    float4 aR = loadA(ks), wR = loadW(ks);
    for (int k0 = ks; k0 < ke; k0 += 16) {
        As[akc + 0][ar] = aR.x;
        As[akc + 1][ar] = aR.y;
        As[akc + 2][ar] = aR.z;
        As[akc + 3][ar] = aR.w;
        *(float4*)&Ws[wk][wnc] = wR;
        __syncthreads();
        if (k0 + 16 < ke) { aR = loadA(k0 + 16); wR = loadW(k0 + 16); }
#pragma unroll
        for (int kk = 0; kk < 16; kk++) {
            float4 a = *(const float4*)&As[kk][ty * 4];
            float4 b = *(const float4*)&Ws[kk][tx * 4];
            float av[4] = {a.x, a.y, a.z, a.w};
            float bv[4] = {b.x, b.y, b.z, b.w};
#pragma unroll
            for (int i = 0; i < 4; i++)
#pragma unroll
                for (int j = 0; j < 4; j++) acc[i][j] += av[i] * bv[j];
        }
        __syncthreads();
    }
#pragma unroll
    for (int i = 0; i < 4; i++) {
#pragma unroll
        for (int j = 0; j < 4; j++) {
            int nn = n0 + tx * 4 + j;
            if (nn < N)
                atomicAdd(&out[(size_t)(m0 + ty * 4 + i) * N + nn], acc[i][j]);
        }
    }
}

// Kernel 7: elementwise bias (+ optional leaky), src -> dst
__global__ __launch_bounds__(256) void bias_act(
    const float* __restrict__ src, const float* __restrict__ bias,
    float* __restrict__ dst, int total, int N, int leaky) {
    int i = blockIdx.x * 256 + threadIdx.x;
    int stride = gridDim.x * 256;
    for (; i < total; i += stride) {
        float v = src[i] + bias[i % N];
        if (leaky) v = v > 0.f ? v : 0.01f * v;
        dst[i] = v;
    }
}

// ---------------------------------------------------------------------------
extern "C" void kernel_launch(void* const* d_in, const int* in_sizes, int n_in,
                              void* d_out, int out_size, void* d_ws, size_t ws_size,
                              hipStream_t stream) {
    const float* embeds    = (const float*)d_in[0];
    const int*   spans     = (const int*)d_in[1];   // int64 ref -> int32 device
    const float* aw1       = (const float*)d_in[2];
    const float* ab1       = (const float*)d_in[3];
    const float* aw2       = (const float*)d_in[4];
    // d_in[5] = ab2: softmax shift-invariant -> unused
    const float* width_emb = (const float*)d_in[6];
    const float* sw1 = (const float*)d_in[7],  *sb1 = (const float*)d_in[8];
    const float* sw2 = (const float*)d_in[9],  *sb2 = (const float*)d_in[10];
    const float* sw3 = (const float*)d_in[11], *sb3 = (const float*)d_in[12];
    const float* sw4 = (const float*)d_in[13], *sb4 = (const float*)d_in[14];
    float* out = (float*)d_out;

    char* ws = (char*)d_ws;
    float*     attns    = (float*)ws;                              // 512 KB
    int*       pos_list = (int*)(ws + (size_t)MAXPOS * 4);         // 512 KB
    int*       meta     = (int*)(ws + (size_t)MAXPOS * 8);         // 4 KB
    _Float16*  WbT      = (_Float16*)(ws + (size_t)MAXPOS * 8 + 4096);  // 1.5 MB
    float* x  = (float*)(ws + (size_t)MAXPOS * 8 + 4096 + (size_t)NPAD * D_ * 2);
    float* y1 = x + (size_t)B_ * XDIM;        // 256*1024
    float* y2 = y1 + (size_t)B_ * 1024;       // 256*512
    float* y3 = y2 + (size_t)B_ * 512;        // 256*256
    float* y4 = y3 + (size_t)B_ * 256;        // 256*30
    size_t ybytes = ((size_t)B_ * (1024 + 512 + 256 + 30)) * 4;

    hipMemsetAsync(y1, 0, ybytes, stream);    // split-K accumulators
    hipMemsetAsync(attns, 0, (size_t)MAXPOS * 4, stream);  // attn partial sums
    scan_kernel<<<1, 256, 0, stream>>>(spans, meta);
    pos_fill<<<B_, 256, 0, stream>>>(meta, pos_list);
    transpose_w<<<dim3(D_ / 32, NPAD / 32), 256, 0, stream>>>(aw1, WbT);
    attn_gemm_v4<<<dim3(MAXPOS / BM, NPAD / BN), 512, 0, stream>>>(
        embeds, WbT, ab1, aw2, pos_list, meta, attns);
    build_x<<<dim3(B_, 3), 256, 0, stream>>>(embeds, attns, meta, width_emb, x);

    mlp_gemm_sk<<<dim3(4, 16, 8), 256, 0, stream>>>(x,  nullptr, 0, sw1, y1, B_, 1024, XDIM, 292);
    mlp_gemm_sk<<<dim3(4, 8, 8), 256, 0, stream>>>(y1, sb1, 1, sw2, y2, B_, 512, 1024, 128);
    mlp_gemm_sk<<<dim3(4, 4, 8), 256, 0, stream>>>(y2, sb2, 1, sw3, y3, B_, 256, 512, 64);
    mlp_gemm_sk<<<dim3(4, 1, 8), 256, 0, stream>>>(y3, sb3, 1, sw4, y4, B_, 30, 256, 32);
    bias_act<<<30, 256, 0, stream>>>(y4, sb4, out, B_ * 30, 30, 0);
}